// Round 2
// baseline (897.059 us; speedup 1.0000x reference)
//
#include <hip/hip_runtime.h>

#define NN 100000
#define NE 1600000
#define HID 64

// ---- edge-index dtype detection -------------------------------------------
// Reference creates int64 edges; harness convention converts ints to int32.
// Detect at runtime: int64 data (values < 2^31, nonneg) has all-zero odd
// int32 words. 64 consecutive odd words all zero => int64 (P ~ 1e-320 for
// genuine int32 edges uniform in [0, 1e5)).
__global__ void k_detect(const int* __restrict__ ei, int* __restrict__ flag) {
    int t = threadIdx.x;  // 64 threads
    int v = ei[2 * t + 1];
    unsigned long long b = __ballot(v != 0);
    if (t == 0) *flag = (b == 0ULL) ? 1 : 0;  // 1 => int64 layout
}

__device__ __forceinline__ int ld_idx(const int* __restrict__ ei, int off, int is64) {
    // logical element `off` in a flat [2*NE] index array
    return is64 ? ei[2 * off] : ei[off];
}

// ---- degree / normalization ------------------------------------------------
__global__ void k_init_deg(float* __restrict__ deg) {
    int i = blockIdx.x * 256 + threadIdx.x;
    if (i < NN) deg[i] = 1.0f;  // self loop
}

__global__ void k_count(const int* __restrict__ ei, float* __restrict__ deg,
                        const int* __restrict__ flag) {
    int e = blockIdx.x * 256 + threadIdx.x;
    int f = *flag;
    if (e < NE) atomicAdd(&deg[ld_idx(ei, NE + e, f)], 1.0f);
}

__global__ void k_dinv(float* __restrict__ deg) {
    int i = blockIdx.x * 256 + threadIdx.x;
    if (i < NN) deg[i] = 1.0f / sqrtf(deg[i]);
}

// ---- layer 1: h_pre = x@W1, hs = h_pre*dinv, acc init = hs (self loop) -----
// 256 threads = 4 nodes/block, 64 lanes (one wave) per node.
__global__ void k_layer1(const float* __restrict__ x, const float* __restrict__ W1,
                         const float* __restrict__ dinv,
                         float* __restrict__ hs, float* __restrict__ acc) {
    int t = threadIdx.x;
    int node = blockIdx.x * 4 + (t >> 6);
    int c = t & 63;
    float4 xv = *(const float4*)(x + node * 4);
    float v = xv.x * W1[c] + xv.y * W1[64 + c] +
              xv.z * W1[128 + c] + xv.w * W1[192 + c];
    float s = v * dinv[node];
    hs[node * 64 + c]  = s;
    acc[node * 64 + c] = s;
}

// ---- edge scatter: acc[dst] += hs[src] (one wave per edge) -----------------
__global__ void k_scatter(const int* __restrict__ ei,
                          const float* __restrict__ hs, float* __restrict__ acc,
                          const int* __restrict__ flag) {
    int t = threadIdx.x;
    int e = blockIdx.x * 4 + (t >> 6);
    int c = t & 63;
    int f = *flag;
    int s = ld_idx(ei, e, f);
    int d = ld_idx(ei, NE + e, f);
    atomicAdd(&acc[d * 64 + c], hs[s * 64 + c]);
}

// ---- layer 2: h1 = relu(dinv*acc + b1); hs/acc = (h1@W2)*dinv --------------
__global__ void k_layer2(const float* __restrict__ W2, const float* __restrict__ b1,
                         const float* __restrict__ dinv,
                         float* __restrict__ hs, float* __restrict__ acc) {
    __shared__ float sW2[64 * 64];
    __shared__ float sh1[4][64];
    int t = threadIdx.x;
#pragma unroll
    for (int r = 0; r < 16; ++r) sW2[r * 256 + t] = W2[r * 256 + t];
    int node = blockIdx.x * 4 + (t >> 6);
    int c = t & 63;
    float d = dinv[node];
    sh1[t >> 6][c] = fmaxf(fmaf(d, acc[node * 64 + c], b1[c]), 0.0f);
    __syncthreads();
    const float* h1 = sh1[t >> 6];
    float sum = 0.0f;
#pragma unroll
    for (int k = 0; k < 64; ++k) sum = fmaf(h1[k], sW2[k * 64 + c], sum);
    float s2 = sum * d;
    hs[node * 64 + c]  = s2;   // layer-1 hs no longer needed
    acc[node * 64 + c] = s2;   // self-loop init (own row only -> no hazard)
}

// ---- head: logits = relu(dinv*acc + b2) @ Wl + bl --------------------------
__global__ void k_head(const float* __restrict__ b2, const float* __restrict__ Wl,
                       const float* __restrict__ bl, const float* __restrict__ dinv,
                       const float* __restrict__ acc, float* __restrict__ out) {
    int t = threadIdx.x;
    int node = blockIdx.x * 4 + (t >> 6);
    int c = t & 63;
    float d = dinv[node];
    float h2 = fmaxf(fmaf(d, acc[node * 64 + c], b2[c]), 0.0f);
    float v = h2 * Wl[c];
#pragma unroll
    for (int off = 32; off; off >>= 1) v += __shfl_down(v, off, 64);
    if (c == 0) out[node] = v + bl[0];
}

extern "C" void kernel_launch(void* const* d_in, const int* in_sizes, int n_in,
                              void* d_out, int out_size, void* d_ws, size_t ws_size,
                              hipStream_t stream) {
    const float* x  = (const float*)d_in[0];
    const int*   ei = (const int*)d_in[1];   // [2, NE] flat; dtype auto-detected
    const float* W1 = (const float*)d_in[2];
    const float* b1 = (const float*)d_in[3];
    const float* W2 = (const float*)d_in[4];
    const float* b2 = (const float*)d_in[5];
    const float* Wl = (const float*)d_in[6];
    const float* bl = (const float*)d_in[7];
    float* out = (float*)d_out;

    float* ws   = (float*)d_ws;
    float* dinv = ws;                        // NN floats
    float* hs   = ws + NN;                   // NN*HID floats
    float* acc  = ws + NN + NN * HID;        // NN*HID floats
    int*   flag = (int*)(ws + NN + 2 * NN * HID);  // 1 int (~51.6 MB total)

    hipLaunchKernelGGL(k_detect,   dim3(1), dim3(64), 0, stream, ei, flag);
    hipLaunchKernelGGL(k_init_deg, dim3((NN + 255) / 256), dim3(256), 0, stream, dinv);
    hipLaunchKernelGGL(k_count,    dim3((NE + 255) / 256), dim3(256), 0, stream, ei, dinv, flag);
    hipLaunchKernelGGL(k_dinv,     dim3((NN + 255) / 256), dim3(256), 0, stream, dinv);

    hipLaunchKernelGGL(k_layer1,  dim3(NN / 4), dim3(256), 0, stream, x, W1, dinv, hs, acc);
    hipLaunchKernelGGL(k_scatter, dim3(NE / 4), dim3(256), 0, stream, ei, hs, acc, flag);
    hipLaunchKernelGGL(k_layer2,  dim3(NN / 4), dim3(256), 0, stream, W2, b1, dinv, hs, acc);
    hipLaunchKernelGGL(k_scatter, dim3(NE / 4), dim3(256), 0, stream, ei, hs, acc, flag);
    hipLaunchKernelGGL(k_head,    dim3(NN / 4), dim3(256), 0, stream, b2, Wl, bl, dinv, acc, out);
}

// Round 3
// 444.982 us; speedup vs baseline: 2.0159x; 2.0159x over previous
//
#include <hip/hip_runtime.h>

#define NN 100000
#define NE 1600000
#define HID 64
#define SCAN_B 512
#define NB ((NN + SCAN_B - 1) / SCAN_B)   // 196 scan blocks

// ---- edge-index dtype detection (int64 vs int32), as in R2 -----------------
__global__ void k_detect(const int* __restrict__ ei, int* __restrict__ flag) {
    int t = threadIdx.x;  // 64 threads
    int v = ei[2 * t + 1];
    unsigned long long b = __ballot(v != 0);
    if (t == 0) *flag = (b == 0ULL) ? 1 : 0;  // 1 => int64 layout
}

__device__ __forceinline__ int ld_idx(const int* __restrict__ ei, int off, int is64) {
    return is64 ? ei[2 * off] : ei[off];
}

// ---- CSR build -------------------------------------------------------------
__global__ void k_zero(int* __restrict__ cnt) {
    int i = blockIdx.x * 256 + threadIdx.x;
    if (i < NN) cnt[i] = 0;
}

__global__ void k_count(const int* __restrict__ ei, int* __restrict__ cnt,
                        const int* __restrict__ flag) {
    int e = blockIdx.x * 256 + threadIdx.x;
    int f = *flag;
    if (e < NE) atomicAdd(&cnt[ld_idx(ei, NE + e, f)], 1);
}

// dinv = 1/sqrt(deg), deg = cnt + 1 (self loop); xs = dinv * x  (dim 4)
__global__ void k_dinv_xs(const int* __restrict__ cnt, const float* __restrict__ x,
                          float* __restrict__ dinv, float* __restrict__ xs) {
    int i = blockIdx.x * 256 + threadIdx.x;
    if (i >= NN) return;
    float d = 1.0f / sqrtf((float)(cnt[i] + 1));
    dinv[i] = d;
    float4 xv = ((const float4*)x)[i];
    float4 o; o.x = d * xv.x; o.y = d * xv.y; o.z = d * xv.z; o.w = d * xv.w;
    ((float4*)xs)[i] = o;
}

__global__ void k_scan1(const int* __restrict__ cnt, int* __restrict__ offs,
                        int* __restrict__ bsum) {
    __shared__ int s[SCAN_B];
    int t = threadIdx.x;
    int i = blockIdx.x * SCAN_B + t;
    int v = (i < NN) ? cnt[i] : 0;
    s[t] = v; __syncthreads();
    for (int off = 1; off < SCAN_B; off <<= 1) {
        int u = (t >= off) ? s[t - off] : 0;
        __syncthreads();
        s[t] += u;
        __syncthreads();
    }
    if (i < NN) offs[i] = s[t] - v;            // exclusive within block
    if (t == SCAN_B - 1) bsum[blockIdx.x] = s[t];
}

__global__ void k_scan2(const int* __restrict__ bsum, int* __restrict__ bpre) {
    __shared__ int s[256];
    int t = threadIdx.x;
    int v = (t < NB) ? bsum[t] : 0;
    s[t] = v; __syncthreads();
    for (int off = 1; off < 256; off <<= 1) {
        int u = (t >= off) ? s[t - off] : 0;
        __syncthreads();
        s[t] += u;
        __syncthreads();
    }
    if (t < NB) bpre[t] = s[t] - v;            // exclusive block prefix
}

__global__ void k_scan3(int* __restrict__ offs, const int* __restrict__ bpre,
                        int* __restrict__ cursor) {
    int i = blockIdx.x * 256 + threadIdx.x;
    if (i >= NN) return;
    int o = offs[i] + bpre[i / SCAN_B];
    offs[i] = o;
    cursor[i] = o;
}

__global__ void k_fill(const int* __restrict__ ei, const int* __restrict__ flag,
                       int* __restrict__ cursor, int* __restrict__ csr) {
    int e = blockIdx.x * 256 + threadIdx.x;
    if (e >= NE) return;
    int f = *flag;
    int s = ld_idx(ei, e, f);
    int d = ld_idx(ei, NE + e, f);
    int p = atomicAdd(&cursor[d], 1);
    csr[p] = s;
}

// ---- layer-1 aggregation on raw dim-4 features: agg = dinv*(sum xs[src] + dinv*x)
__global__ void k_agg1(const float* __restrict__ x, const float* __restrict__ xs,
                       const float* __restrict__ dinv, const int* __restrict__ offs,
                       const int* __restrict__ cnt, const int* __restrict__ csr,
                       float* __restrict__ agg) {
    int i = blockIdx.x * 256 + threadIdx.x;
    if (i >= NN) return;
    float sx = 0.f, sy = 0.f, sz = 0.f, sw = 0.f;
    int b = offs[i], n = cnt[i];
    for (int j = 0; j < n; ++j) {
        int s = csr[b + j];
        float4 v = ((const float4*)xs)[s];
        sx += v.x; sy += v.y; sz += v.z; sw += v.w;
    }
    float d = dinv[i];
    float4 xi = ((const float4*)x)[i];
    float4 o;
    o.x = d * (sx + d * xi.x);
    o.y = d * (sy + d * xi.y);
    o.z = d * (sz + d * xi.z);
    o.w = d * (sw + d * xi.w);
    ((float4*)agg)[i] = o;
}

// ---- h1 = relu(agg@W1 + b1); hs = dinv * (h1@W2). 4 nodes/block, wave/node.
__global__ void k_mm(const float* __restrict__ agg, const float* __restrict__ W1,
                     const float* __restrict__ b1, const float* __restrict__ W2,
                     const float* __restrict__ dinv, float* __restrict__ hs) {
    __shared__ float sW2[64 * 64];
    __shared__ float sh1[4][64];
    int t = threadIdx.x;
#pragma unroll
    for (int r = 0; r < 16; ++r) sW2[r * 256 + t] = W2[r * 256 + t];
    int node = blockIdx.x * 4 + (t >> 6);
    int c = t & 63;
    float4 a = ((const float4*)agg)[node];
    float h = a.x * W1[c] + a.y * W1[64 + c] + a.z * W1[128 + c] + a.w * W1[192 + c];
    h = fmaxf(h + b1[c], 0.0f);
    sh1[t >> 6][c] = h;
    __syncthreads();
    const float* h1 = sh1[t >> 6];
    float sum = 0.0f;
#pragma unroll
    for (int k = 0; k < 64; ++k) sum = fmaf(h1[k], sW2[k * 64 + c], sum);
    hs[node * 64 + c] = sum * dinv[node];
}

// ---- layer-2 gather + head, fused. One wave per node. ----------------------
__global__ void k_gather_head(const float* __restrict__ hs, const int* __restrict__ offs,
                              const int* __restrict__ cnt, const int* __restrict__ csr,
                              const float* __restrict__ dinv, const float* __restrict__ b2,
                              const float* __restrict__ Wl, const float* __restrict__ bl,
                              float* __restrict__ out) {
    int t = threadIdx.x;
    int node = blockIdx.x * 4 + (t >> 6);
    int c = t & 63;
    int b = offs[node], n = cnt[node];
    float a = hs[node * 64 + c];                 // self loop (hs already *dinv[self])
    int myidx = (c < n) ? csr[b + c] : 0;        // prefetch up to 64 indices
    int m = n < 64 ? n : 64;
    for (int j = 0; j < m; ++j) {
        int s = __shfl(myidx, j, 64);
        a += hs[s * 64 + c];
    }
    for (int j = 64; j < n; ++j) {               // rare: deg > 64
        int s = csr[b + j];
        a += hs[s * 64 + c];
    }
    float h2 = fmaxf(fmaf(dinv[node], a, b2[c]), 0.0f);
    float v = h2 * Wl[c];
#pragma unroll
    for (int off = 32; off; off >>= 1) v += __shfl_down(v, off, 64);
    if (c == 0) out[node] = v + bl[0];
}

extern "C" void kernel_launch(void* const* d_in, const int* in_sizes, int n_in,
                              void* d_out, int out_size, void* d_ws, size_t ws_size,
                              hipStream_t stream) {
    const float* x  = (const float*)d_in[0];
    const int*   ei = (const int*)d_in[1];
    const float* W1 = (const float*)d_in[2];
    const float* b1 = (const float*)d_in[3];
    const float* W2 = (const float*)d_in[4];
    const float* b2 = (const float*)d_in[5];
    const float* Wl = (const float*)d_in[6];
    const float* bl = (const float*)d_in[7];
    float* out = (float*)d_out;

    // workspace layout (all 16B-aligned: NN,NE multiples of 4)
    char* w = (char*)d_ws;
    float* dinv   = (float*)w;                 w += NN * 4;
    int*   cnt    = (int*)w;                   w += NN * 4;
    int*   offs   = (int*)w;                   w += NN * 4;
    int*   cursor = (int*)w;                   w += NN * 4;
    int*   csr    = (int*)w;                   w += NE * 4;
    float* xs     = (float*)w;                 w += NN * 4 * 4;
    float* agg    = (float*)w;                 w += NN * 4 * 4;
    float* hs     = (float*)w;                 w += NN * HID * 4;
    int*   bsum   = (int*)w;                   w += 256 * 4;
    int*   bpre   = (int*)w;                   w += 256 * 4;
    int*   flag   = (int*)w;                   w += 4;   // ~37 MB total

    const int GN = (NN + 255) / 256;   // per-node grids
    const int GE = (NE + 255) / 256;   // per-edge grids

    hipLaunchKernelGGL(k_detect,  dim3(1),   dim3(64),     0, stream, ei, flag);
    hipLaunchKernelGGL(k_zero,    dim3(GN),  dim3(256),    0, stream, cnt);
    hipLaunchKernelGGL(k_count,   dim3(GE),  dim3(256),    0, stream, ei, cnt, flag);
    hipLaunchKernelGGL(k_dinv_xs, dim3(GN),  dim3(256),    0, stream, cnt, x, dinv, xs);
    hipLaunchKernelGGL(k_scan1,   dim3(NB),  dim3(SCAN_B), 0, stream, cnt, offs, bsum);
    hipLaunchKernelGGL(k_scan2,   dim3(1),   dim3(256),    0, stream, bsum, bpre);
    hipLaunchKernelGGL(k_scan3,   dim3(GN),  dim3(256),    0, stream, offs, bpre, cursor);
    hipLaunchKernelGGL(k_fill,    dim3(GE),  dim3(256),    0, stream, ei, flag, cursor, csr);

    hipLaunchKernelGGL(k_agg1, dim3(GN), dim3(256), 0, stream,
                       x, xs, dinv, offs, cnt, csr, agg);
    hipLaunchKernelGGL(k_mm, dim3(NN / 4), dim3(256), 0, stream,
                       agg, W1, b1, W2, dinv, hs);
    hipLaunchKernelGGL(k_gather_head, dim3(NN / 4), dim3(256), 0, stream,
                       hs, offs, cnt, csr, dinv, b2, Wl, bl, out);
}